// Round 3
// baseline (17544.218 us; speedup 1.0000x reference)
//
#include <hip/hip_runtime.h>
#include <hip/hip_cooperative_groups.h>

namespace cg = cooperative_groups;

// HyperLSTM + MDN decoder — f32 in, f32 out.
// R9: single persistent cooperative kernel (1 launch total). Per step:
// phase A (tile GEMMs) -> grid.sync -> phase B (hh/ch + z + proj epilogue)
// -> grid.sync -> phase C (einsum + LSTM update) -> grid.sync.
// Eliminates ~50 us/step of dispatch latency (4 launches/step in R8).
#define MM     20
#define LATENT 128
#define IN_DIM 133
#define HD     1024
#define HD4    4096
#define HY     256
#define FF     64
#define NSEQ   128
#define BB     64
#define OUT_DIM 123   // 6*M+3
#define GRID   256
#define TPB    512

// Persistent state + per-step intermediates in __device__ globals.
__device__ float g_h   [BB * HD];
__device__ float g_c   [BB * HD];
__device__ float g_hh  [BB * HY];
__device__ float g_chP [2][BB * HY];   // parity-buffered (intra-phase race fix)
__device__ float g_hWh [4][BB * HD4];
__device__ float g_xWx [BB * HD4];
__device__ float g_gH  [4][BB * HD];
__device__ float g_ghh [BB * HD];
__device__ float g_gx  [BB * HD];
__device__ float g_z   [BB * 3 * HY];
__device__ float g_proj[4][BB * 128];

__device__ __forceinline__ float sigf(float x) { return 1.0f / (1.0f + expf(-x)); }

__device__ __forceinline__ void gload_lds16(const float* g, float* l) {
    __builtin_amdgcn_global_load_lds(
        (const __attribute__((address_space(1))) void*)g,
        (__attribute__((address_space(3))) void*)l, 16, 0, 0);
}

struct Params {
    const float *z, *strokes, *fc_in_w, *fc_in_b, *fc_proj_w, *fc_proj_b;
    const float *Wx, *Wh, *b0w, *Wxh_hy, *Whh_hy, *b_hy;
    const float *Wzx, *bzx, *Wzh, *bzh, *Wzb, *Dx, *Dh, *Db;
    float* out;
};

// 64b x 128c tile GEMM, k-chunk <= 256, 4x4 register blocking (R8-verified).
__device__ __forceinline__ void tile_gemm(
    const float* __restrict__ Ap, int lda, int kl, bool aS,
    const float* __restrict__ Wp, int ldw, int co, bool wS, int ncols,
    const float* __restrict__ bias, float* __restrict__ Op, int ldo,
    int tid, float At[][64][68], float Wt[][64 * 128])
{
    int arow = tid >> 3, aoct = (tid & 7) << 3;
    int lane = tid & 63, wv = tid >> 6;
    int colb = lane & 31, rsub = lane >> 5;
    int cgi = tid & 31, bg = tid >> 5;

    float ar[8];
    int np = (kl + 63) >> 6;
    const float* apr = Ap + arow * lda;

    if (!wS) {
        #pragma unroll
        for (int q = 0; q < 4; q++) {
            int chunk = (wv << 2) + q;
            int kr = (chunk << 1) + rsub; if (kr > kl - 1) kr = kl - 1;
            gload_lds16(Wp + kr * ldw + co + (colb << 2), &Wt[0][chunk << 8]);
        }
    } else {
        #pragma unroll
        for (int q = 0; q < 16; q++) {
            int i2 = (q << 9) + tid, r = i2 >> 7, c = i2 & 127;
            Wt[0][i2] = (c < ncols) ? Wp[r * ldw + c] : 0.f;
        }
    }
    if (!aS) {
        float4 v0 = *(const float4*)(apr + aoct);
        float4 v1 = *(const float4*)(apr + aoct + 4);
        ar[0]=v0.x; ar[1]=v0.y; ar[2]=v0.z; ar[3]=v0.w;
        ar[4]=v1.x; ar[5]=v1.y; ar[6]=v1.z; ar[7]=v1.w;
    } else {
        #pragma unroll
        for (int j = 0; j < 8; j++) { int ka = aoct + j; ar[j] = (ka < kl) ? apr[ka] : 0.f; }
    }
    #pragma unroll
    for (int j = 0; j < 8; j++) At[0][aoct + j][arow] = ar[j];
    __syncthreads();

    float4 acc0 = {0,0,0,0}, acc1 = {0,0,0,0}, acc2 = {0,0,0,0}, acc3 = {0,0,0,0};

    for (int pp = 0; pp < np; pp++) {
        int cur = pp & 1, nxt = cur ^ 1;
        int kb = (pp + 1) << 6;
        bool pref = (pp + 1 < np);
        if (pref) {                 // issue-early: loads land under compute
            if (!wS) {
                #pragma unroll
                for (int q = 0; q < 4; q++) {
                    int chunk = (wv << 2) + q;
                    int kr = kb + (chunk << 1) + rsub; if (kr > kl - 1) kr = kl - 1;
                    gload_lds16(Wp + kr * ldw + co + (colb << 2), &Wt[nxt][chunk << 8]);
                }
            } else {
                #pragma unroll
                for (int q = 0; q < 16; q++) {
                    int i2 = (q << 9) + tid, r = i2 >> 7, c = i2 & 127;
                    int kr = kb + r; if (kr > kl - 1) kr = kl - 1;
                    Wt[nxt][i2] = (c < ncols) ? Wp[kr * ldw + c] : 0.f;
                }
            }
            if (!aS) {
                float4 v0 = *(const float4*)(apr + kb + aoct);
                float4 v1 = *(const float4*)(apr + kb + aoct + 4);
                ar[0]=v0.x; ar[1]=v0.y; ar[2]=v0.z; ar[3]=v0.w;
                ar[4]=v1.x; ar[5]=v1.y; ar[6]=v1.z; ar[7]=v1.w;
            } else {
                #pragma unroll
                for (int j = 0; j < 8; j++) {
                    int ka = kb + aoct + j;
                    ar[j] = (ka < kl) ? apr[ka] : 0.f;
                }
            }
        }
        const float* Ac = &At[cur][0][0];
        const float* Wc = &Wt[cur][0];
        #pragma unroll 8
        for (int k = 0; k < 64; k++) {
            float4 av  = *(const float4*)(Ac + k * 68 + (bg << 2));
            float4 wv4 = *(const float4*)(Wc + (k << 7) + (cgi << 2));
            acc0.x += av.x * wv4.x; acc0.y += av.x * wv4.y;
            acc0.z += av.x * wv4.z; acc0.w += av.x * wv4.w;
            acc1.x += av.y * wv4.x; acc1.y += av.y * wv4.y;
            acc1.z += av.y * wv4.z; acc1.w += av.y * wv4.w;
            acc2.x += av.z * wv4.x; acc2.y += av.z * wv4.y;
            acc2.z += av.z * wv4.z; acc2.w += av.z * wv4.w;
            acc3.x += av.w * wv4.x; acc3.y += av.w * wv4.y;
            acc3.z += av.w * wv4.z; acc3.w += av.w * wv4.w;
        }
        if (pref) {
            #pragma unroll
            for (int j = 0; j < 8; j++) At[nxt][aoct + j][arow] = ar[j];
        }
        __syncthreads();
    }

    int cc = co + (cgi << 2);
    if (bias) {
        float4 bv = *(const float4*)(bias + cc);
        acc0.x += bv.x; acc0.y += bv.y; acc0.z += bv.z; acc0.w += bv.w;
        acc1.x += bv.x; acc1.y += bv.y; acc1.z += bv.z; acc1.w += bv.w;
        acc2.x += bv.x; acc2.y += bv.y; acc2.z += bv.z; acc2.w += bv.w;
        acc3.x += bv.x; acc3.y += bv.y; acc3.z += bv.z; acc3.w += bv.w;
    }
    float* op = Op + (bg << 2) * ldo + cc;
    *(float4*)(op)           = acc0;
    *(float4*)(op + ldo)     = acc1;
    *(float4*)(op + 2 * ldo) = acc2;
    *(float4*)(op + 3 * ldo) = acc3;
}

__global__ __launch_bounds__(TPB, 1) void fused(Params p)
{
    cg::grid_group gridg = cg::this_grid();

    __shared__ float At[2][64][68];       // 34.8 KB
    __shared__ float Wt[2][64 * 128];     // 64 KB
    __shared__ float zC[8][768];          // 24.6 KB
    __shared__ float preC[8][4][32];      // 4 KB
    __shared__ float gsum[1024];          // 4 KB
    __shared__ float hhB[256];            // 1 KB   -> total 131 KB <= 160 KB

    int blk = blockIdx.x, tid = threadIdx.x;

    // ---- init: s0 = tanh(z @ fc_in_w + fc_in_b) ----
    if (blk < BB) {
        int b = blk;
        if (tid < LATENT) gsum[tid] = p.z[b * LATENT + tid];
        __syncthreads();
        for (int j = tid; j < 2560; j += TPB) {
            float acc = p.fc_in_b[j];
            #pragma unroll 4
            for (int k = 0; k < LATENT; k++) acc += gsum[k] * p.fc_in_w[k * 2560 + j];
            float s = tanhf(acc);
            if      (j < 1024) g_h [b * 1024 + j]          = s;
            else if (j < 2048) g_c [b * 1024 + (j - 1024)] = s;
            else if (j < 2304) g_hh[b * 256  + (j - 2048)] = s;
            else               g_chP[0][b * 256 + (j - 2304)] = s;
        }
    }
    gridg.sync();

    for (int t = 0; t <= NSEQ; t++) {
        // ================= phase A: tile GEMMs =================
        {
            int u = blk;
            bool run = false;
            const float* Ap = nullptr; int lda = 0, kl = 0; bool aS = false;
            const float* Wp = nullptr; int ldw = 0, co = 0; bool wS = false; int ncols = 0;
            const float* bias = nullptr; float* Op = nullptr; int ldo = 0;
            if (u < 4) {                            // proj of h_{t-1}
                if (t > 0) {
                    run = true;
                    Ap = g_h + u * 256; lda = HD; kl = 256;
                    Wp = p.fc_proj_w + u * 256 * OUT_DIM; ldw = OUT_DIM; co = 0;
                    wS = true; ncols = OUT_DIM;
                    Op = g_proj[u]; ldo = 128;
                }
            } else if (t < NSEQ) {
                run = true;
                if (u < 132) {                      // h @ Wh
                    int i = u - 4, ct = i & 31, ch = i >> 5;
                    Ap = g_h + ch * 256; lda = HD; kl = 256;
                    Wp = p.Wh + ch * 256 * HD4; ldw = HD4; co = ct * 128;
                    Op = g_hWh[ch]; ldo = HD4;
                } else if (u < 164) {               // x @ Wx
                    int ct = u - 132;
                    Ap = p.strokes + t * BB * IN_DIM; lda = IN_DIM; kl = IN_DIM; aS = true;
                    Wp = p.Wx; ldw = HD4; co = ct * 128;
                    Op = g_xWx; ldo = HD4;
                } else if (u < 196) {               // h part of hyper gates
                    int i = u - 164, ct = i & 7, ch = i >> 3;
                    Ap = g_h + ch * 256; lda = HD; kl = 256;
                    Wp = p.Wxh_hy + (133 + ch * 256) * HD; ldw = HD; co = ct * 128;
                    Op = g_gH[ch]; ldo = HD;
                } else if (u < 204) {               // hh @ Whh_hy
                    int ct = u - 196;
                    Ap = g_hh; lda = HY; kl = HY;
                    Wp = p.Whh_hy; ldw = HD; co = ct * 128;
                    Op = g_ghh; ldo = HD;
                } else if (u < 212) {               // x part of hyper gates (+b_hy)
                    int ct = u - 204;
                    Ap = p.strokes + t * BB * IN_DIM; lda = IN_DIM; kl = IN_DIM; aS = true;
                    Wp = p.Wxh_hy; ldw = HD; co = ct * 128;
                    bias = p.b_hy; Op = g_gx; ldo = HD;
                } else run = false;                 // [212,256) idle
            }
            if (run) tile_gemm(Ap, lda, kl, aS, Wp, ldw, co, wS, ncols,
                               bias, Op, ldo, tid, At, Wt);
        }
        gridg.sync();

        // ================= phase B: hh/ch update + z + proj epilogue =========
        {
            int b = blk >> 2, q = blk & 3;
            if (t < NSEQ) {
                int base = b * HD;
                #pragma unroll
                for (int half = 0; half < 2; half++) {
                    int j = tid + half * TPB;
                    gsum[j] = g_gx[base + j] + g_ghh[base + j]
                            + g_gH[0][base + j] + g_gH[1][base + j]
                            + g_gH[2][base + j] + g_gH[3][base + j];
                }
                __syncthreads();
                if (tid < 256) {
                    float gi = gsum[tid],       gf = gsum[256 + tid];
                    float gG = gsum[512 + tid], go = gsum[768 + tid];
                    int par = t & 1;
                    float ch = g_chP[par][b * HY + tid];
                    ch = sigf(gf) * ch + sigf(gi) * tanhf(gG);
                    float hh = sigf(go) * tanhf(ch);
                    if (q == 0) {
                        g_chP[par ^ 1][b * HY + tid] = ch;
                        g_hh[b * HY + tid] = hh;
                    }
                    hhB[tid] = hh;
                }
                __syncthreads();
                if (tid < 192) {                    // z outputs [q*192, q*192+192)
                    int o = q * 192 + tid;
                    int ten = o >> 8, oo = o & 255;
                    const float* Wz = (ten == 0) ? p.Wzx : (ten == 1) ? p.Wzh : p.Wzb;
                    float acc = (ten == 0) ? p.bzx[oo] : (ten == 1) ? p.bzh[oo] : 0.f;
                    #pragma unroll 8
                    for (int k = 0; k < HY; k++) acc += hhB[k] * Wz[k * HY + oo];
                    g_z[b * 768 + o] = acc;
                }
            }
            if (t > 0 && q == 3 && tid >= 384) {    // proj epilogue + MDN, tp = t-1
                int c = tid - 384, tp = t - 1, base = b << 7;
                if (c < 120) {
                    float v = g_proj[0][base + c] + g_proj[1][base + c]
                            + g_proj[2][base + c] + g_proj[3][base + c]
                            + p.fc_proj_b[c];
                    int m = c / 6, r = c - m * 6;
                    int oidx = tp * (MM * BB) + m * BB + b;
                    if      (r == 0) p.out[oidx]          = 1.0f;  // size-1 softmax
                    else if (r == 1) p.out[163840 + oidx] = v;
                    else if (r == 2) p.out[327680 + oidx] = v;
                    else if (r == 3) p.out[491520 + oidx] = expf(v);
                    else if (r == 4) p.out[655360 + oidx] = expf(v);
                    else             p.out[819200 + oidx] = tanhf(v);
                } else if (c == 120) {              // pen-state softmax
                    float p0 = g_proj[0][base+120] + g_proj[1][base+120]
                             + g_proj[2][base+120] + g_proj[3][base+120] + p.fc_proj_b[120];
                    float p1 = g_proj[0][base+121] + g_proj[1][base+121]
                             + g_proj[2][base+121] + g_proj[3][base+121] + p.fc_proj_b[121];
                    float p2 = g_proj[0][base+122] + g_proj[1][base+122]
                             + g_proj[2][base+122] + g_proj[3][base+122] + p.fc_proj_b[122];
                    float mx = fmaxf(p0, fmaxf(p1, p2));
                    float e0 = expf(p0 - mx), e1 = expf(p1 - mx), e2 = expf(p2 - mx);
                    float s = e0 + e1 + e2;
                    int ob = 983040 + tp * (BB * 3) + b * 3;
                    p.out[ob + 0] = e0 / s; p.out[ob + 1] = e1 / s; p.out[ob + 2] = e2 / s;
                }
            }
        }
        if (t == NSEQ) break;                       // tail done (uniform)
        gridg.sync();

        // ================= phase C: einsum + main LSTM update ================
        {
            int bg = blk >> 5, sl = blk & 31;
            int hi0 = sl * 32;
            {
                const float4* src = (const float4*)(g_z + bg * 8 * 768);
                float4* dst = (float4*)&zC[0][0];
                for (int i = tid; i < 1536; i += TPB) dst[i] = src[i];
            }
            __syncthreads();
            int hi_l = tid & 31, gq = (tid >> 5) & 3, b4 = tid >> 7;
            int hi = hi0 + hi_l;
            const float* dxp = p.Dx + gq * 64 * HD + hi;
            const float* dhp = p.Dh + gq * 64 * HD + hi;
            const float* dbp = p.Db + gq * 64 * HD + hi;
            const float* zx0 = &zC[b4][gq * 64];
            const float* zh0 = &zC[b4][256 + gq * 64];
            const float* zb0 = &zC[b4][512 + gq * 64];
            const float* zx1 = &zC[b4 + 4][gq * 64];
            const float* zh1 = &zC[b4 + 4][256 + gq * 64];
            const float* zb1 = &zC[b4 + 4][512 + gq * 64];
            float ax0 = 0.f, ah0 = 0.f, ab0 = 0.f, ax1 = 0.f, ah1 = 0.f, ab1 = 0.f;
            #pragma unroll 4
            for (int f = 0; f < FF; f++) {
                float dx = dxp[f * HD], dh = dhp[f * HD], db = dbp[f * HD];
                ax0 += zx0[f] * dx; ah0 += zh0[f] * dh; ab0 += zb0[f] * db;
                ax1 += zx1[f] * dx; ah1 += zh1[f] * dh; ab1 += zb1[f] * db;
            }
            int idx = gq * HD + hi;
            int b0i = bg * 8 + b4, b1i = b0i + 4;
            float hw0 = g_hWh[0][b0i * HD4 + idx] + g_hWh[1][b0i * HD4 + idx]
                      + g_hWh[2][b0i * HD4 + idx] + g_hWh[3][b0i * HD4 + idx];
            float hw1 = g_hWh[0][b1i * HD4 + idx] + g_hWh[1][b1i * HD4 + idx]
                      + g_hWh[2][b1i * HD4 + idx] + g_hWh[3][b1i * HD4 + idx];
            float pre0 = ax0 * g_xWx[b0i * HD4 + idx] + ah0 * hw0 + ab0 + p.b0w[idx];
            float pre1 = ax1 * g_xWx[b1i * HD4 + idx] + ah1 * hw1 + ab1 + p.b0w[idx];
            preC[b4][gq][hi_l]     = pre0;
            preC[b4 + 4][gq][hi_l] = pre1;
            __syncthreads();
            if (tid < 256) {
                int bi = tid >> 5, hl = tid & 31;
                int b = bg * 8 + bi, ha = b * HD + hi0 + hl;
                float pi = preC[bi][0][hl], pf = preC[bi][1][hl];
                float pg = preC[bi][2][hl], po = preC[bi][3][hl];
                float cv = g_c[ha];
                float nc = sigf(pf) * cv + sigf(pi) * tanhf(pg);
                float nh = sigf(po) * tanhf(nc);
                g_c[ha] = nc;
                g_h[ha] = nh;
            }
        }
        gridg.sync();
    }
}

// ---------------------------------------------------------------------------
extern "C" void kernel_launch(void* const* d_in, const int* in_sizes, int n_in,
                              void* d_out, int out_size, void* d_ws, size_t ws_size,
                              hipStream_t stream)
{
    Params p;
    p.z         = (const float*)d_in[0];
    p.strokes   = (const float*)d_in[1];
    p.fc_in_w   = (const float*)d_in[2];
    p.fc_in_b   = (const float*)d_in[3];
    p.fc_proj_w = (const float*)d_in[4];
    p.fc_proj_b = (const float*)d_in[5];
    p.Wx        = (const float*)d_in[6];
    p.Wh        = (const float*)d_in[7];
    p.b0w       = (const float*)d_in[8];
    p.Wxh_hy    = (const float*)d_in[9];
    p.Whh_hy    = (const float*)d_in[10];
    p.b_hy      = (const float*)d_in[11];
    p.Wzx       = (const float*)d_in[12];
    p.bzx       = (const float*)d_in[13];
    p.Wzh       = (const float*)d_in[14];
    p.bzh       = (const float*)d_in[15];
    p.Wzb       = (const float*)d_in[16];
    p.Dx        = (const float*)d_in[17];
    p.Dh        = (const float*)d_in[18];
    p.Db        = (const float*)d_in[19];
    p.out       = (float*)d_out;
    (void)d_ws; (void)ws_size; (void)in_sizes; (void)n_in; (void)out_size;

    void* args[] = { (void*)&p };
    hipLaunchCooperativeKernel((const void*)fused, dim3(GRID), dim3(TPB),
                               args, 0, stream);
}

// Round 4
// 8464.755 us; speedup vs baseline: 2.0726x; 2.0726x over previous
//
#include <hip/hip_runtime.h>

// HyperLSTM + MDN decoder — f32 in, f32 out.
// R10: back to stream launches (coop grid.sync cost ~35us/sync — R9 rocprof).
// K1 rebuilt VALU-bound: A operands pre-transposed in GLOBAL (g_hT/g_hhT/g_xT),
// read as broadcast float4 (no LDS A-staging -> no 8-way transpose-write bank
// conflicts, R9's 9.3e7 SQ_LDS_BANK_CONFLICT). 8bx4c register blocking:
// per k-step 1 ds_read_b128 + 2 broadcast dwordx4 + 32 FMA. Uniform k=64
// split-K units (808 blocks), W staged via global_load_lds_dwordx4.
// 3 launches/step: K1 (all GEMMs) -> K2 (gates+hh/ch+z+proj/MDN) -> K3.
#define MM     20
#define LATENT 128
#define IN_DIM 133
#define HD     1024
#define HD4    4096
#define HY     256
#define FF     64
#define NSEQ   128
#define BB     64
#define OUT_DIM 123   // 6*M+3
#define NU     808    // K1 unit count

// Persistent state + per-step intermediates (transposed layouts: [k][b]).
__device__ float g_hT  [HD * BB];        // h(t-1), transposed
__device__ float g_c   [BB * HD];
__device__ float g_ch  [BB * HY];
__device__ float g_hhT [HY * BB];        // hh, transposed
__device__ float g_xT  [NSEQ * 192 * BB]; // strokes transposed, k-padded to 192
__device__ float g_hWh [16][BB * HD4];   // h@Wh split-K partials (k-chunks of 64)
__device__ float g_xWx [3][BB * HD4];
__device__ float g_gH  [16][BB * HD];    // h-part of hyper gates
__device__ float g_ghh [4][BB * HD];     // hh@Whh_hy
__device__ float g_gx  [3][BB * HD];     // x-part of hyper gates
__device__ float g_z   [BB * 3 * HY];
__device__ float g_proj[16][BB * 128];   // proj split-K partials

__device__ __forceinline__ float sigf(float x) { return 1.0f / (1.0f + expf(-x)); }

__device__ __forceinline__ void gload_lds16(const float* g, float* l) {
    __builtin_amdgcn_global_load_lds(
        (const __attribute__((address_space(1))) void*)g,
        (__attribute__((address_space(3))) void*)l, 16, 0, 0);
}

// ---------------------------------------------------------------------------
// init: s0 = tanh(z @ fc_in_w + fc_in_b) -> hT0, c0, hhT0, ch0.  grid 64 x 256
// ---------------------------------------------------------------------------
__global__ __launch_bounds__(256) void init_kernel(
    const float* __restrict__ z, const float* __restrict__ fc_in_w,
    const float* __restrict__ fc_in_b)
{
    int b = blockIdx.x, tid = threadIdx.x;
    __shared__ float zs[LATENT];
    if (tid < LATENT) zs[tid] = z[b * LATENT + tid];
    __syncthreads();
    for (int j = tid; j < 2560; j += 256) {
        float acc = fc_in_b[j];
        #pragma unroll 4
        for (int k = 0; k < LATENT; k++) acc += zs[k] * fc_in_w[k * 2560 + j];
        float s = tanhf(acc);
        if      (j < 1024) g_hT [j * 64 + b]               = s;
        else if (j < 2048) g_c  [b * 1024 + (j - 1024)]    = s;
        else if (j < 2304) g_hhT[(j - 2048) * 64 + b]      = s;
        else               g_ch [b * 256 + (j - 2304)]     = s;
    }
}

// ---------------------------------------------------------------------------
// xT: one-time strokes transpose, zero-padded k to 192.  grid 128 x 256
// ---------------------------------------------------------------------------
__global__ __launch_bounds__(256) void xt_kernel(const float* __restrict__ strokes)
{
    int t = blockIdx.x, tid = threadIdx.x;
    for (int i = tid; i < 192 * 64; i += 256) {
        int k = i >> 6, b = i & 63;
        g_xT[t * 192 * 64 + i] =
            (k < IN_DIM) ? strokes[(t * BB + b) * IN_DIM + k] : 0.f;
    }
}

// ---------------------------------------------------------------------------
// K1: uniform tile GEMM, 64 b x 128 cols, k-chunk = 64. 256 threads, 8bx4c.
// A from global transposed panels (broadcast float4); W LDS via gload_lds.
// Unit map:
//   [0,16)    proj   16 k-chunks -> g_proj[ch]     (epilogue in K2)
//   [16,528)  hWh    16 ch x 32 ct -> g_hWh[ch]
//   [528,624) xWx    3 ch x 32 ct  -> g_xWx[ch]
//   [624,752) gH     16 ch x 8 ct  -> g_gH[ch]
//   [752,784) ghh    4 ch x 8 ct   -> g_ghh[ch]
//   [784,808) gx     3 ch x 8 ct   -> g_gx[ch]
// Tail launch (t==NSEQ): grid=16 (proj only).
// ---------------------------------------------------------------------------
__global__ __launch_bounds__(256, 4) void k1_kernel(
    const float* __restrict__ Wx,      const float* __restrict__ Wh,
    const float* __restrict__ Wxh_hy,  const float* __restrict__ Whh_hy,
    const float* __restrict__ fc_proj_w, int t)
{
    __shared__ float Wt[64 * 128];   // 32 KB
    int u = blockIdx.x, tid = threadIdx.x;

    const float* AT; const float* Wp; int ldw, wrow0, wrows, co;
    float* Op; int ldo; bool wS = false;

    if (u < 16) {                               // proj (h_{t-1})
        if (t == 0) return;
        AT = g_hT + u * 64 * 64;
        Wp = fc_proj_w; ldw = OUT_DIM; wrow0 = u * 64; wrows = HD; wS = true;
        Op = g_proj[u]; ldo = 128; co = 0;
    } else if (t >= NSEQ) { return;
    } else if (u < 528) {                       // h @ Wh
        int i = u - 16, ch = i >> 5, ct = i & 31;
        AT = g_hT + ch * 64 * 64;
        Wp = Wh; ldw = HD4; wrow0 = ch * 64; wrows = HD;
        Op = g_hWh[ch]; ldo = HD4; co = ct * 128;
    } else if (u < 624) {                       // x @ Wx
        int i = u - 528, ch = i >> 5, ct = i & 31;
        AT = g_xT + (t * 192 + ch * 64) * 64;
        Wp = Wx; ldw = HD4; wrow0 = ch * 64; wrows = IN_DIM;   // clamp; av=0 kills pad
        Op = g_xWx[ch]; ldo = HD4; co = ct * 128;
    } else if (u < 752) {                       // h part of hyper gates
        int i = u - 624, ch = i >> 3, ct = i & 7;
        AT = g_hT + ch * 64 * 64;
        Wp = Wxh_hy + 133 * HD; ldw = HD; wrow0 = ch * 64; wrows = HD;
        Op = g_gH[ch]; ldo = HD; co = ct * 128;
    } else if (u < 784) {                       // hh @ Whh_hy
        int i = u - 752, ch = i >> 3, ct = i & 7;
        AT = g_hhT + ch * 64 * 64;
        Wp = Whh_hy; ldw = HD; wrow0 = ch * 64; wrows = HY;
        Op = g_ghh[ch]; ldo = HD; co = ct * 128;
    } else {                                    // x part of hyper gates
        int i = u - 784, ch = i >> 3, ct = i & 7;
        AT = g_xT + (t * 192 + ch * 64) * 64;
        Wp = Wxh_hy; ldw = HD; wrow0 = ch * 64; wrows = IN_DIM; // av=0 kills pad
        Op = g_gx[ch]; ldo = HD; co = ct * 128;
    }

    // ---- stage W panel [64 k][128 c] ----
    if (!wS) {
        #pragma unroll
        for (int i = 0; i < 8; i++) {
            int s = (i << 8) + tid;             // 0..2047 float4 slots
            int r = s >> 5, cq = s & 31;
            int kr = wrow0 + r; if (kr > wrows - 1) kr = wrows - 1;
            gload_lds16(Wp + kr * ldw + co + (cq << 2), &Wt[s << 2]);
        }
    } else {                                    // proj: ldw=123, pad cols to 128
        for (int i = 0; i < 32; i++) {
            int idx = (i << 8) + tid;
            int r = idx >> 7, c = idx & 127;
            Wt[idx] = (c < OUT_DIM) ? Wp[(wrow0 + r) * OUT_DIM + c] : 0.f;
        }
    }
    __syncthreads();

    // ---- compute: 8 b-rows x 4 cols per thread ----
    int cq = tid & 31, bq = tid >> 5;
    const float* ATb = AT + (bq << 3);
    const float* Wc  = Wt + (cq << 2);
    float4 acc0 = {0,0,0,0}, acc1 = {0,0,0,0}, acc2 = {0,0,0,0}, acc3 = {0,0,0,0};
    float4 acc4 = {0,0,0,0}, acc5 = {0,0,0,0}, acc6 = {0,0,0,0}, acc7 = {0,0,0,0};
    #pragma unroll 8
    for (int k = 0; k < 64; k++) {
        float4 a0 = *(const float4*)(ATb + (k << 6));
        float4 a1 = *(const float4*)(ATb + (k << 6) + 4);
        float4 w  = *(const float4*)(Wc + (k << 7));
        acc0.x += a0.x*w.x; acc0.y += a0.x*w.y; acc0.z += a0.x*w.z; acc0.w += a0.x*w.w;
        acc1.x += a0.y*w.x; acc1.y += a0.y*w.y; acc1.z += a0.y*w.z; acc1.w += a0.y*w.w;
        acc2.x += a0.z*w.x; acc2.y += a0.z*w.y; acc2.z += a0.z*w.z; acc2.w += a0.z*w.w;
        acc3.x += a0.w*w.x; acc3.y += a0.w*w.y; acc3.z += a0.w*w.z; acc3.w += a0.w*w.w;
        acc4.x += a1.x*w.x; acc4.y += a1.x*w.y; acc4.z += a1.x*w.z; acc4.w += a1.x*w.w;
        acc5.x += a1.y*w.x; acc5.y += a1.y*w.y; acc5.z += a1.y*w.z; acc5.w += a1.y*w.w;
        acc6.x += a1.z*w.x; acc6.y += a1.z*w.y; acc6.z += a1.z*w.z; acc6.w += a1.z*w.w;
        acc7.x += a1.w*w.x; acc7.y += a1.w*w.y; acc7.z += a1.w*w.z; acc7.w += a1.w*w.w;
    }
    float* op = Op + (bq << 3) * ldo + co + (cq << 2);
    *(float4*)(op)           = acc0;
    *(float4*)(op + ldo)     = acc1;
    *(float4*)(op + 2 * ldo) = acc2;
    *(float4*)(op + 3 * ldo) = acc3;
    *(float4*)(op + 4 * ldo) = acc4;
    *(float4*)(op + 5 * ldo) = acc5;
    *(float4*)(op + 6 * ldo) = acc6;
    *(float4*)(op + 7 * ldo) = acc7;
}

// ---------------------------------------------------------------------------
// K2: per b: gate-sum (16+4+3 partials + b_hy) -> hh/ch update -> z GEMV.
//     tid>=256 concurrently: proj epilogue + MDN for step t-1.
// grid 64 x 512.
// ---------------------------------------------------------------------------
__global__ __launch_bounds__(512) void k2_kernel(
    const float* __restrict__ b_hy,
    const float* __restrict__ Wzx, const float* __restrict__ bzx,
    const float* __restrict__ Wzh, const float* __restrict__ bzh,
    const float* __restrict__ Wzb,
    const float* __restrict__ fc_proj_b, float* __restrict__ out, int t)
{
    __shared__ float gsum[1024];
    __shared__ float hhB[256];
    int b = blockIdx.x, tid = threadIdx.x;

    if (t < NSEQ) {
        int base = b * HD;
        #pragma unroll
        for (int half = 0; half < 2; half++) {
            int j = (half << 9) + tid;
            float a = b_hy[j];
            #pragma unroll
            for (int q = 0; q < 16; q++) a += g_gH[q][base + j];
            #pragma unroll
            for (int q = 0; q < 4; q++)  a += g_ghh[q][base + j];
            #pragma unroll
            for (int q = 0; q < 3; q++)  a += g_gx[q][base + j];
            gsum[j] = a;
        }
    }
    __syncthreads();
    if (t < NSEQ && tid < 256) {
        float gi = gsum[tid],       gf = gsum[256 + tid];
        float gg = gsum[512 + tid], go = gsum[768 + tid];
        float ch = g_ch[b * HY + tid];
        ch = sigf(gf) * ch + sigf(gi) * tanhf(gg);
        float hh = sigf(go) * tanhf(ch);
        g_ch[b * HY + tid] = ch;
        g_hhT[tid * 64 + b] = hh;
        hhB[tid] = hh;
    }
    if (t > 0 && tid >= 256) {                  // proj epilogue + MDN, tp = t-1
        int c = tid - 256, tp = t - 1, base7 = b << 7;
        if (c < 120) {
            float v = fc_proj_b[c];
            #pragma unroll
            for (int q = 0; q < 16; q++) v += g_proj[q][base7 + c];
            int m = c / 6, r = c - m * 6;
            int oidx = tp * (MM * BB) + m * BB + b;
            if      (r == 0) out[oidx]          = 1.0f;   // size-1 softmax
            else if (r == 1) out[163840 + oidx] = v;
            else if (r == 2) out[327680 + oidx] = v;
            else if (r == 3) out[491520 + oidx] = expf(v);
            else if (r == 4) out[655360 + oidx] = expf(v);
            else             out[819200 + oidx] = tanhf(v);
        } else if (c == 120) {                  // pen-state softmax
            float p0 = fc_proj_b[120], p1 = fc_proj_b[121], p2 = fc_proj_b[122];
            #pragma unroll
            for (int q = 0; q < 16; q++) {
                p0 += g_proj[q][base7 + 120];
                p1 += g_proj[q][base7 + 121];
                p2 += g_proj[q][base7 + 122];
            }
            float mx = fmaxf(p0, fmaxf(p1, p2));
            float e0 = expf(p0 - mx), e1 = expf(p1 - mx), e2 = expf(p2 - mx);
            float s = e0 + e1 + e2;
            int ob = 983040 + tp * (BB * 3) + b * 3;
            out[ob + 0] = e0 / s; out[ob + 1] = e1 / s; out[ob + 2] = e2 / s;
        }
    }
    __syncthreads();
    if (t < NSEQ) {
        for (int o = tid; o < 768; o += 512) {
            int ten = o >> 8, oo = o & 255;
            const float* Wz = (ten == 0) ? Wzx : (ten == 1) ? Wzh : Wzb;
            float acc = (ten == 0) ? bzx[oo] : (ten == 1) ? bzh[oo] : 0.f;
            #pragma unroll 8
            for (int k = 0; k < HY; k++) acc += hhB[k] * Wz[(k << 8) + oo];
            g_z[b * 768 + o] = acc;
        }
    }
}

// ---------------------------------------------------------------------------
// K3: einsum (z x D) + combine split-K partials + main LSTM update (+hT write).
// grid 256 = 8 b-groups(8 b) x 32 hi-slices(32).
// ---------------------------------------------------------------------------
__global__ __launch_bounds__(512) void k3_kernel(
    const float* __restrict__ Dx, const float* __restrict__ Dh,
    const float* __restrict__ Db, const float* __restrict__ b0w)
{
    __shared__ float zC[8][768];
    __shared__ float preC[8][4][32];
    int blk = blockIdx.x, tid = threadIdx.x;
    int bg = blk >> 5, sl = blk & 31;
    int hi0 = sl * 32;
    {
        const float4* src = (const float4*)(g_z + bg * 8 * 768);
        float4* dst = (float4*)&zC[0][0];
        for (int i = tid; i < 1536; i += 512) dst[i] = src[i];
    }
    __syncthreads();
    int hi_l = tid & 31, gq = (tid >> 5) & 3, b4 = tid >> 7;
    int hi = hi0 + hi_l;
    const float* dxp = Dx + gq * 64 * HD + hi;
    const float* dhp = Dh + gq * 64 * HD + hi;
    const float* dbp = Db + gq * 64 * HD + hi;
    const float* zx0 = &zC[b4][gq * 64];
    const float* zh0 = &zC[b4][256 + gq * 64];
    const float* zb0 = &zC[b4][512 + gq * 64];
    const float* zx1 = &zC[b4 + 4][gq * 64];
    const float* zh1 = &zC[b4 + 4][256 + gq * 64];
    const float* zb1 = &zC[b4 + 4][512 + gq * 64];
    float ax0 = 0.f, ah0 = 0.f, ab0 = 0.f, ax1 = 0.f, ah1 = 0.f, ab1 = 0.f;
    #pragma unroll 4
    for (int f = 0; f < FF; f++) {
        float dx = dxp[f * HD], dh = dhp[f * HD], db = dbp[f * HD];
        ax0 += zx0[f] * dx; ah0 += zh0[f] * dh; ab0 += zb0[f] * db;
        ax1 += zx1[f] * dx; ah1 += zh1[f] * dh; ab1 += zb1[f] * db;
    }
    int idx = gq * HD + hi;
    int b0i = bg * 8 + b4, b1i = b0i + 4;
    float hw0 = 0.f, hw1 = 0.f, xw0 = 0.f, xw1 = 0.f;
    #pragma unroll
    for (int q = 0; q < 16; q++) {
        hw0 += g_hWh[q][b0i * HD4 + idx];
        hw1 += g_hWh[q][b1i * HD4 + idx];
    }
    #pragma unroll
    for (int q = 0; q < 3; q++) {
        xw0 += g_xWx[q][b0i * HD4 + idx];
        xw1 += g_xWx[q][b1i * HD4 + idx];
    }
    float pre0 = ax0 * xw0 + ah0 * hw0 + ab0 + b0w[idx];
    float pre1 = ax1 * xw1 + ah1 * hw1 + ab1 + b0w[idx];
    preC[b4][gq][hi_l]     = pre0;
    preC[b4 + 4][gq][hi_l] = pre1;
    __syncthreads();
    if (tid < 256) {
        int bi = tid >> 5, hl = tid & 31;
        int b = bg * 8 + bi, ha = b * HD + hi0 + hl;
        float pi = preC[bi][0][hl], pf = preC[bi][1][hl];
        float pg = preC[bi][2][hl], po = preC[bi][3][hl];
        float cv = g_c[ha];
        float nc = sigf(pf) * cv + sigf(pi) * tanhf(pg);
        float nh = sigf(po) * tanhf(nc);
        g_c[ha] = nc;
        g_hT[(hi0 + hl) * 64 + b] = nh;
    }
}

// ---------------------------------------------------------------------------
extern "C" void kernel_launch(void* const* d_in, const int* in_sizes, int n_in,
                              void* d_out, int out_size, void* d_ws, size_t ws_size,
                              hipStream_t stream)
{
    const float* z         = (const float*)d_in[0];
    const float* strokes   = (const float*)d_in[1];
    const float* fc_in_w   = (const float*)d_in[2];
    const float* fc_in_b   = (const float*)d_in[3];
    const float* fc_proj_w = (const float*)d_in[4];
    const float* fc_proj_b = (const float*)d_in[5];
    const float* Wx        = (const float*)d_in[6];
    const float* Wh        = (const float*)d_in[7];
    const float* b0w       = (const float*)d_in[8];
    const float* Wxh_hy    = (const float*)d_in[9];
    const float* Whh_hy    = (const float*)d_in[10];
    const float* b_hy      = (const float*)d_in[11];
    const float* Wzx       = (const float*)d_in[12];
    const float* bzx       = (const float*)d_in[13];
    const float* Wzh       = (const float*)d_in[14];
    const float* bzh       = (const float*)d_in[15];
    const float* Wzb       = (const float*)d_in[16];
    const float* Dx        = (const float*)d_in[17];
    const float* Dh        = (const float*)d_in[18];
    const float* Db        = (const float*)d_in[19];
    (void)d_ws; (void)ws_size; (void)in_sizes; (void)n_in; (void)out_size;
    float* out = (float*)d_out;

    init_kernel<<<64, 256, 0, stream>>>(z, fc_in_w, fc_in_b);
    xt_kernel<<<128, 256, 0, stream>>>(strokes);
    for (int t = 0; t < NSEQ; t++) {
        k1_kernel<<<NU, 256, 0, stream>>>(Wx, Wh, Wxh_hy, Whh_hy, fc_proj_w, t);
        k2_kernel<<<64, 512, 0, stream>>>(b_hy, Wzx, bzx, Wzh, bzh, Wzb,
                                          fc_proj_b, out, t);
        k3_kernel<<<256, 512, 0, stream>>>(Dx, Dh, Db, b0w);
    }
    // tail: proj + MDN for t = 127
    k1_kernel<<<16, 256, 0, stream>>>(Wx, Wh, Wxh_hy, Whh_hy, fc_proj_w, NSEQ);
    k2_kernel<<<64, 512, 0, stream>>>(b_hy, Wzx, bzx, Wzh, bzh, Wzb,
                                      fc_proj_b, out, NSEQ);
}